// Round 9
// baseline (33.187 us; speedup 1.0000x reference)
//
#include <hip/hip_runtime.h>
#include <hip/hip_bf16.h>
#include <math.h>

// DiffusionLoss, fully closed-form — no GEMM, no matrix, no per-element h.
//
// M = norm_lap; v_i = u_i/||u||, u_i = sqrt(deg_i+1e-6) is an EXACT null
// vector of M (incl. the +1e-6). Deflation + degree-1 expansion (validated
// absmax 0.0 in rounds 4-8):
//   heat_ij = a*v_i*v_j + b*delta_ij + g*Wt_ij,  Wt_ij = rs_i*adj_ij*rs_j
//   a = 1-e^-tau(1+tau), b = e^-tau, g = tau*e^-tau.
// Column mean/var reduce algebraically to per-node scalars
// (c_i = a*u_i*Sinv; ub = mean(u); Tuu = sum (u-ub)^2):
//   m_i  = c_i*ub + g*rs_i*W1_i/N + b/N
//   (N-1)var_i = c^2*Tuu + b^2(1-1/N) + (g*rs)^2*(W2 - W1^2/N)
//              + 2*c*g*rs*WU + 2*c*b*(u_i-ub) - 2*g*b*rs*W1/N
// with per-column sums (tau-independent, j != i):
//   W1 = sum adj*rs_j, W2 = sum (adj*rs_j)^2, WU = sum adj*rs_j*(u_j-ub).
//
// adj = sigmoid(1 - d/50); over reachable d in [0,~10], cubic Taylor at d=5
// matches exp+rcp to <= 2.5e-6 abs (v_sqrt is the only transcendental/eval).
//
// Round-6 lesson: no cross-block fences. Round-9: k_final is replaced by ONE
// device-scope float atomicAdd per k_W block (block pre-reduced; out zeroed
// by k_deg across the kernel boundary). 2 dispatches total — the remaining
// budget is per-launch overhead (~8us each, round 7->8 delta).

#define GN 4096

#define PC0 0.7109495f
#define PC1 0.2055003f
#define PC2 -0.0433502f
#define PC3 -0.0079812f

__device__ __forceinline__ float poly_adj(float xi, float yi, float zi,
                                          float xj, float yj, float zj) {
  float dx = xi - xj, dy = yi - yj, dz = zi - zj;
  float d2 = fmaf(dx, dx, fmaf(dy, dy, dz * dz));
  float d = __builtin_amdgcn_sqrtf(d2);
  float h = fmaf(d, -0.02f, 0.1f);
  return fmaf(h, fmaf(h, fmaf(h, PC3, PC2), PC1), PC0);
}

// Pass 1: deg, 4 rows per block (1024 blocks -> 16 waves/CU).
// Block 0 also zeroes out[0] (visible to k_W via end-of-kernel release).
__global__ __launch_bounds__(256) void k_deg(const float* __restrict__ pos,
                                             float* __restrict__ deg,
                                             float* __restrict__ out) {
  const int b = blockIdx.x, t = threadIdx.x;
  const int lane = t & 63, wid = t >> 6;
  if (b == 0 && t == 0) out[0] = 0.0f;
  float xi[4], yi[4], zi[4], s[4];
#pragma unroll
  for (int r = 0; r < 4; ++r) {
    int i = 4 * b + r;  // block-uniform -> scalar regs
    xi[r] = pos[3 * i]; yi[r] = pos[3 * i + 1]; zi[r] = pos[3 * i + 2];
    s[r] = 0.0f;
  }
  for (int q = 0; q < GN / 256; ++q) {
    int j = t + 256 * q;
    float xj = pos[3 * j], yj = pos[3 * j + 1], zj = pos[3 * j + 2];
#pragma unroll
    for (int r = 0; r < 4; ++r) {
      float a = poly_adj(xi[r], yi[r], zi[r], xj, yj, zj);
      s[r] += (j == 4 * b + r) ? 0.0f : a;  // zero diagonal
    }
  }
  __shared__ float red[4][4];
#pragma unroll
  for (int r = 0; r < 4; ++r) {
#pragma unroll
    for (int off = 32; off > 0; off >>= 1) s[r] += __shfl_down(s[r], off, 64);
    if (lane == 0) red[r][wid] = s[r];
  }
  __syncthreads();
  if (t < 4) deg[4 * b + t] = red[t][0] + red[t][1] + red[t][2] + red[t][3];
}

// Pass 2: per-block prologue rebuilds ub/Sinv/Tuu + LDS rs/uc tables from
// deg (identical in every block -> bitwise identical), then W1/W2/WU for 4
// columns; cv finished in-block; ONE atomicAdd into out.
__global__ __launch_bounds__(256) void k_W(const float* __restrict__ pos,
                                           const float* __restrict__ deg,
                                           float* __restrict__ out) {
  const int b = blockIdx.x, t = threadIdx.x;
  const int lane = t & 63, wid = t >> 6;
  const int c0 = 4 * b;
  __shared__ float rs_l[GN];  // 16 KB: 1/u_j
  __shared__ float uc_l[GN];  // 16 KB: u_j - ub
  __shared__ float rA[4], rB[4];

  // ---- prologue (fast rsq: u = dd*rsq(dd), rs = rsq(dd); ~1e-7 rel)
  float S = 0.0f, Su = 0.0f, ul[GN / 256];
#pragma unroll
  for (int q = 0; q < GN / 256; ++q) {
    int i = t + 256 * q;
    float dd = deg[i] + 1e-6f;
    float rsq = __builtin_amdgcn_rsqf(dd);
    float u = dd * rsq;
    rs_l[i] = rsq;
    ul[q] = u;
    S += dd;
    Su += u;
  }
#pragma unroll
  for (int off = 32; off > 0; off >>= 1) {
    S += __shfl_down(S, off, 64);
    Su += __shfl_down(Su, off, 64);
  }
  if (lane == 0) { rA[wid] = S; rB[wid] = Su; }
  __syncthreads();
  S = rA[0] + rA[1] + rA[2] + rA[3];
  Su = rB[0] + rB[1] + rB[2] + rB[3];
  const float ub = Su * (1.0f / GN);
  const float Sinv = 1.0f / S;
  float Tu = 0.0f;
#pragma unroll
  for (int q = 0; q < GN / 256; ++q) {
    int i = t + 256 * q;
    float um = ul[q] - ub;
    uc_l[i] = um;
    Tu = fmaf(um, um, Tu);
  }
  __syncthreads();  // rA reads done; uc/rs visible
#pragma unroll
  for (int off = 32; off > 0; off >>= 1) Tu += __shfl_down(Tu, off, 64);
  if (lane == 0) rA[wid] = Tu;
  __syncthreads();
  const float Tuu = rA[0] + rA[1] + rA[2] + rA[3];

  // ---- main: 4 columns per block
  float cx[4], cy[4], cz[4], W1[4], W2[4], WU[4];
#pragma unroll
  for (int r = 0; r < 4; ++r) {
    int i = c0 + r;  // block-uniform -> scalar regs
    cx[r] = pos[3 * i]; cy[r] = pos[3 * i + 1]; cz[r] = pos[3 * i + 2];
    W1[r] = 0.0f; W2[r] = 0.0f; WU[r] = 0.0f;
  }
  for (int q = 0; q < GN / 256; ++q) {
    int j = t + 256 * q;
    float xj = pos[3 * j], yj = pos[3 * j + 1], zj = pos[3 * j + 2];
    float rsj = rs_l[j], ucj = uc_l[j];
#pragma unroll
    for (int r = 0; r < 4; ++r) {
      float aw = poly_adj(cx[r], cy[r], cz[r], xj, yj, zj);
      float tt = aw * rsj;             // adj * rs_j
      tt = (j == c0 + r) ? 0.0f : tt;  // zero diagonal
      W1[r] += tt;
      W2[r] = fmaf(tt, tt, W2[r]);
      WU[r] = fmaf(tt, ucj, WU[r]);
    }
  }
  __syncthreads();
  __shared__ float red[12][4];
#pragma unroll
  for (int r = 0; r < 4; ++r) {
#pragma unroll
    for (int off = 32; off > 0; off >>= 1) {
      W1[r] += __shfl_down(W1[r], off, 64);
      W2[r] += __shfl_down(W2[r], off, 64);
      WU[r] += __shfl_down(WU[r], off, 64);
    }
    if (lane == 0) {
      red[r][wid] = W1[r];
      red[4 + r][wid] = W2[r];
      red[8 + r][wid] = WU[r];
    }
  }
  __syncthreads();
  __shared__ float cvs[4];
  if (t < 4) {
    const int i = c0 + t;
    float w1 = red[t][0] + red[t][1] + red[t][2] + red[t][3];
    float w2 = red[4 + t][0] + red[4 + t][1] + red[4 + t][2] + red[4 + t][3];
    float wu = red[8 + t][0] + red[8 + t][1] + red[8 + t][2] + red[8 + t][3];
    const float e5 = 6.737946999085467e-3f;     // e^-5
    const float e10 = 4.5399929762484854e-5f;   // e^-10
    const float a5 = 0.9595723180054872f;       // 1 - 6 e^-5
    const float g5 = 0.033689734995427335f;     // 5 e^-5
    const float a10 = 0.9995006007726127f;      // 1 - 11 e^-10
    const float g10 = 4.5399929762484856e-4f;   // 10 e^-10
    const float rn = 1.0f / GN, rn1 = 1.0f / (GN - 1);
    float um = uc_l[i];
    float u = um + ub;
    float rs = rs_l[i];
    float Wm = w1 * rn;
    float cenW = fmaf(-w1, Wm, w2);
    // tau = 5
    float c = a5 * u * Sinv;
    float m = fmaf(c, ub, fmaf(g5 * rs, Wm, e5 * rn));
    float gr = g5 * rs;
    float sd2 = c * c * Tuu + e5 * e5 * (1.0f - rn) + gr * gr * cenW +
                2.0f * c * gr * wu + 2.0f * c * e5 * um - 2.0f * e5 * gr * Wm;
    float cv5 = sqrtf(fmaxf(sd2 * rn1, 0.0f)) / (m + 1e-6f);
    // tau = 10
    c = a10 * u * Sinv;
    m = fmaf(c, ub, fmaf(g10 * rs, Wm, e10 * rn));
    gr = g10 * rs;
    sd2 = c * c * Tuu + e10 * e10 * (1.0f - rn) + gr * gr * cenW +
          2.0f * c * gr * wu + 2.0f * c * e10 * um - 2.0f * e10 * gr * Wm;
    float cv10 = sqrtf(fmaxf(sd2 * rn1, 0.0f)) / (m + 1e-6f);
    cvs[t] = cv5 + cv10;
  }
  __syncthreads();
  if (t == 0)
    atomicAdd(out,
              (cvs[0] + cvs[1] + cvs[2] + cvs[3]) * (1.0f / (2.0f * GN)));
}

extern "C" void kernel_launch(void* const* d_in, const int* in_sizes, int n_in,
                              void* d_out, int out_size, void* d_ws,
                              size_t ws_size, hipStream_t stream) {
  const float* pos = (const float*)d_in[0];
  float* out = (float*)d_out;
  float* deg = (float*)d_ws;

  k_deg<<<GN / 4, 256, 0, stream>>>(pos, deg, out);
  k_W<<<GN / 4, 256, 0, stream>>>(pos, deg, out);
}